// Round 1
// baseline (306.094 us; speedup 1.0000x reference)
//
#include <hip/hip_runtime.h>

// Problem constants
// x: [16, 512, 64, 64] fp32, memory: [1024, 512] fp32
// recon: [16, 512, 64, 64] fp32, match: [16, 64, 64] fp32
#define C_DIM 512
#define K_MEM 1024

typedef __attribute__((ext_vector_type(8))) short short8;   // 8 bf16 in 4 VGPRs
typedef __attribute__((ext_vector_type(4))) float f32x4;
typedef __attribute__((ext_vector_type(4))) unsigned int u32x4;

__device__ __forceinline__ unsigned short f2bf(float f) {
    unsigned int u = __builtin_bit_cast(unsigned int, f);
    unsigned int r = (u + 0x7fffu + ((u >> 16) & 1u)) >> 16;  // RNE
    return (unsigned short)r;
}

__device__ __forceinline__ f32x4 mfma16(short8 a, short8 b, f32x4 c) {
    return __builtin_amdgcn_mfma_f32_16x16x32_bf16(a, b, c, 0, 0, 0);
}

// ---------------- prep 1: L2-normalize memory rows -> bf16 Mn[k][c] ----------------
__global__ __launch_bounds__(256)
void prep_norm(const float* __restrict__ mem, unsigned short* __restrict__ Mn) {
    int k = blockIdx.x, t = threadIdx.x;
    const float* row = mem + (size_t)k * C_DIM;
    float2 v = *reinterpret_cast<const float2*>(row + 2 * t);
    float ss = v.x * v.x + v.y * v.y;
#pragma unroll
    for (int off = 32; off >= 1; off >>= 1) ss += __shfl_xor(ss, off);
    __shared__ float wp[4];
    if ((t & 63) == 0) wp[t >> 6] = ss;
    __syncthreads();
    float tot = wp[0] + wp[1] + wp[2] + wp[3];
    float rn = 1.0f / fmaxf(sqrtf(tot), 1e-12f);
    unsigned int pk = (unsigned int)f2bf(v.x * rn) | ((unsigned int)f2bf(v.y * rn) << 16);
    *reinterpret_cast<unsigned int*>(Mn + (size_t)k * C_DIM + 2 * t) = pk;
}

// ---------------- prep 2: transpose Mn[k][c] -> MnT[c][k] (LDS-tiled) ----------------
__global__ __launch_bounds__(256)
void prep_transpose(const unsigned short* __restrict__ Mn, unsigned short* __restrict__ MnT) {
    __shared__ unsigned short tl[64][72];  // +8 pad
    int t = threadIdx.x;
    int bk = blockIdx.x & 15, bc = blockIdx.x >> 4;  // 16 k-tiles x 8 c-tiles
    int k0 = bk * 64, c0 = bc * 64;
    {
        int kr = t >> 2, gc = (t & 3) * 16;
        const u32x4* src = reinterpret_cast<const u32x4*>(Mn + (size_t)(k0 + kr) * C_DIM + c0 + gc);
        u32x4 a = src[0], b = src[1];
        *reinterpret_cast<u32x4*>(&tl[kr][gc]) = a;
        *reinterpret_cast<u32x4*>(&tl[kr][gc + 8]) = b;
    }
    __syncthreads();
    {
        int cr = t >> 2, gk = (t & 3) * 16;
        unsigned int ow[8];
#pragma unroll
        for (int j = 0; j < 8; ++j)
            ow[j] = (unsigned int)tl[gk + 2 * j][cr] | ((unsigned int)tl[gk + 2 * j + 1][cr] << 16);
        unsigned int* dst = reinterpret_cast<unsigned int*>(MnT + (size_t)(c0 + cr) * K_MEM + k0 + gk);
#pragma unroll
        for (int j = 0; j < 8; ++j) dst[j] = ow[j];
    }
}

// ---------------- fused: normalize feats, sim GEMM, softmax (no max-sub), recon GEMM ----------------
__global__ __launch_bounds__(512, 2)
void fused_attn(const float* __restrict__ x,
                const unsigned short* __restrict__ Mn,
                const unsigned short* __restrict__ MnT,
                float* __restrict__ recon,
                float* __restrict__ match) {
    __shared__ unsigned short Fn[64][520];         // normalized feats bf16, +8 pad
    __shared__ alignas(16) char stageB[32768];     // union: Mn [128k][128c] / MnT [512c][32k]
    __shared__ unsigned short Plds[64][136];       // exp(S) bf16, +8 pad
    __shared__ float partS[2][64];
    __shared__ float partM[2][64];
    __shared__ float Zs[64], Ms[64], Zinv[64], rnormS[64];
    __shared__ float normpart[64][9];

    const int t = threadIdx.x;
    const int bid = blockIdx.x;            // 0..1023 = b*64 + h
    const int b = bid >> 6, h = bid & 63;
    const int lane = t & 63, wv = t >> 6;  // 8 waves
    const int l15 = lane & 15, l4 = lane >> 4;

    // ---- phase 0: feature norms + bf16 tile into LDS ----
    {
        const int w = lane, cg = wv;  // 8 c-groups of 64
        const float* xp = x + (size_t)b * 2097152 + (size_t)h * 64 + w;
        float ss = 0.f;
#pragma unroll 4
        for (int i = 0; i < 64; ++i) {
            float v = xp[(size_t)(cg * 64 + i) * 4096];
            ss += v * v;
        }
        normpart[w][cg] = ss;
        if (t < 64) { Zs[t] = 0.f; Ms[t] = -3.0e38f; }
        __syncthreads();
        if (t < 64) {
            float s = 0.f;
#pragma unroll
            for (int j = 0; j < 8; ++j) s += normpart[t][j];
            rnormS[t] = 1.0f / fmaxf(sqrtf(s), 1e-12f);
        }
        __syncthreads();
        float rn = rnormS[w];
#pragma unroll 4
        for (int i = 0; i < 64; i += 2) {
            float v0 = xp[(size_t)(cg * 64 + i) * 4096] * rn;
            float v1 = xp[(size_t)(cg * 64 + i + 1) * 4096] * rn;
            unsigned int pk = (unsigned int)f2bf(v0) | ((unsigned int)f2bf(v1) << 16);
            *reinterpret_cast<unsigned int*>(&Fn[w][cg * 64 + i]) = pk;
        }
    }

    const int rg = wv >> 1, kh = wv & 1;  // GEMM1 roles: 4 rowgroups x 2 k-halves

    f32x4 zero4 = {0.f, 0.f, 0.f, 0.f};
    f32x4 acc3[4][4];
#pragma unroll
    for (int i = 0; i < 4; ++i)
#pragma unroll
        for (int j = 0; j < 4; ++j) acc3[i][j] = zero4;

    u32x4 sreg[4];
    // prologue: GEMM1 stage regs for kt=0, cc=0
#pragma unroll
    for (int j = 0; j < 4; ++j) {
        int o16 = j * 512 + t;
        int row = o16 >> 4;
        int g = (o16 & 15) ^ (row & 15);
        sreg[j] = *reinterpret_cast<const u32x4*>(Mn + (size_t)row * C_DIM + g * 8);
    }

    for (int kt = 0; kt < 8; ++kt) {
        f32x4 acc1[4];
#pragma unroll
        for (int i = 0; i < 4; ++i) acc1[i] = zero4;

        // ---- GEMM1: S[64n x 128k] over c in 4 chunks of 128 ----
        for (int cc = 0; cc < 4; ++cc) {
            __syncthreads();  // previous stage consumers done
#pragma unroll
            for (int j = 0; j < 4; ++j)
                *reinterpret_cast<u32x4*>(stageB + (j * 512 + t) * 16) = sreg[j];
            __syncthreads();  // stage visible
            // issue next stage loads early (hidden under MFMAs)
            if (cc < 3) {
#pragma unroll
                for (int j = 0; j < 4; ++j) {
                    int o16 = j * 512 + t;
                    int row = o16 >> 4;
                    int g = (o16 & 15) ^ (row & 15);
                    sreg[j] = *reinterpret_cast<const u32x4*>(
                        Mn + (size_t)(kt * 128 + row) * C_DIM + (cc + 1) * 128 + g * 8);
                }
            } else {
#pragma unroll
                for (int j = 0; j < 4; ++j) {
                    int o16 = j * 512 + t;
                    int row = o16 >> 2;
                    int g = ((o16 & 3) ^ (row & 3)) ^ ((row >> 2) & 3);
                    sreg[j] = *reinterpret_cast<const u32x4*>(
                        MnT + (size_t)row * K_MEM + kt * 128 + g * 8);
                }
            }
#pragma unroll
            for (int s = 0; s < 4; ++s) {
                short8 af = *reinterpret_cast<const short8*>(&Fn[rg * 16 + l15][cc * 128 + s * 32 + l4 * 8]);
#pragma unroll
                for (int ksb = 0; ksb < 4; ++ksb) {
                    int row = kh * 64 + ksb * 16 + l15;
                    short8 bf = *reinterpret_cast<const short8*>(
                        stageB + row * 256 + (((s * 4 + l4) ^ (row & 15)) << 4));
                    acc1[ksb] = mfma16(af, bf, acc1[ksb]);
                }
            }
        }

        // ---- phase 2: exp(S), row stats, P -> LDS bf16 ----
        float psum[4], pmax[4];
        float pv[4][4];
#pragma unroll
        for (int r = 0; r < 4; ++r) {
            pmax[r] = fmaxf(fmaxf(acc1[0][r], acc1[1][r]), fmaxf(acc1[2][r], acc1[3][r]));
            float s0 = 0.f;
#pragma unroll
            for (int ksb = 0; ksb < 4; ++ksb) {
                float e = __expf(acc1[ksb][r]);
                pv[ksb][r] = e;
                s0 += e;
            }
            psum[r] = s0;
        }
#pragma unroll
        for (int off = 1; off < 16; off <<= 1) {
#pragma unroll
            for (int r = 0; r < 4; ++r) {
                psum[r] += __shfl_xor(psum[r], off);
                pmax[r] = fmaxf(pmax[r], __shfl_xor(pmax[r], off));
            }
        }
        if (l15 == 0) {
#pragma unroll
            for (int r = 0; r < 4; ++r) {
                partS[kh][rg * 16 + l4 * 4 + r] = psum[r];
                partM[kh][rg * 16 + l4 * 4 + r] = pmax[r];
            }
        }
#pragma unroll
        for (int ksb = 0; ksb < 4; ++ksb)
#pragma unroll
            for (int r = 0; r < 4; ++r)
                Plds[rg * 16 + l4 * 4 + r][kh * 64 + ksb * 16 + l15] = f2bf(pv[ksb][r]);
        __syncthreads();
        if (t < 64) {
            Zs[t] += partS[0][t] + partS[1][t];
            Ms[t] = fmaxf(Ms[t], fmaxf(partM[0][t], partM[1][t]));
        }

        // ---- GEMM2 (recon^T): acc3 += MnT-tile x P^T, 4 k-steps of 32 ----
        for (int ks = 0; ks < 4; ++ks) {
            __syncthreads();
#pragma unroll
            for (int j = 0; j < 4; ++j)
                *reinterpret_cast<u32x4*>(stageB + (j * 512 + t) * 16) = sreg[j];
            __syncthreads();
            if (ks < 3) {
#pragma unroll
                for (int j = 0; j < 4; ++j) {
                    int o16 = j * 512 + t;
                    int row = o16 >> 2;
                    int g = ((o16 & 3) ^ (row & 3)) ^ ((row >> 2) & 3);
                    sreg[j] = *reinterpret_cast<const u32x4*>(
                        MnT + (size_t)row * K_MEM + kt * 128 + (ks + 1) * 32 + g * 8);
                }
            } else if (kt < 7) {
#pragma unroll
                for (int j = 0; j < 4; ++j) {
                    int o16 = j * 512 + t;
                    int row = o16 >> 4;
                    int g = (o16 & 15) ^ (row & 15);
                    sreg[j] = *reinterpret_cast<const u32x4*>(
                        Mn + (size_t)((kt + 1) * 128 + row) * C_DIM + g * 8);
                }
            }
            short8 bfr[4];
#pragma unroll
            for (int ns = 0; ns < 4; ++ns) {
                int prow = ns * 16 + l15;
                bfr[ns] = *reinterpret_cast<const short8*>(
                    reinterpret_cast<const char*>(Plds) + prow * 272 + ks * 64 + l4 * 16);
            }
#pragma unroll
            for (int cs = 0; cs < 4; ++cs) {
                int crow = wv * 64 + cs * 16 + l15;
                short8 af = *reinterpret_cast<const short8*>(
                    stageB + crow * 64 + (((l4 ^ (crow & 3)) ^ ((crow >> 2) & 3)) << 4));
#pragma unroll
                for (int ns = 0; ns < 4; ++ns)
                    acc3[cs][ns] = mfma16(af, bfr[ns], acc3[cs][ns]);
            }
        }
    }

    // ---- epilogue ----
    __syncthreads();
    if (t < 64) {
        float zi = 1.0f / Zs[t];
        Zinv[t] = zi;
        match[(size_t)bid * 64 + t] = __expf(Ms[t]) * zi;
    }
    __syncthreads();

    float* rbase = recon + (size_t)b * 2097152 + (size_t)h * 64;
#pragma unroll
    for (int cs = 0; cs < 4; ++cs) {
#pragma unroll
        for (int r = 0; r < 4; ++r) {
            int c = wv * 64 + cs * 16 + l4 * 4 + r;
            float* rp = rbase + (size_t)c * 4096;
#pragma unroll
            for (int ns = 0; ns < 4; ++ns) {
                int n = ns * 16 + l15;
                rp[n] = acc3[cs][ns][r] * Zinv[n];
            }
        }
    }
}

extern "C" void kernel_launch(void* const* d_in, const int* in_sizes, int n_in,
                              void* d_out, int out_size, void* d_ws, size_t ws_size,
                              hipStream_t stream) {
    (void)in_sizes; (void)n_in; (void)out_size;
    if (ws_size < (size_t)2 * 1024 * 1024) return;  // need 2 MB scratch (Mn + MnT bf16)

    const float* x = (const float*)d_in[0];
    const float* mem = (const float*)d_in[1];
    float* recon = (float*)d_out;
    float* match = recon + (size_t)16 * 512 * 64 * 64;
    unsigned short* Mn = (unsigned short*)d_ws;
    unsigned short* MnT = Mn + (size_t)K_MEM * C_DIM;

    prep_norm<<<dim3(K_MEM), dim3(256), 0, stream>>>(mem, Mn);
    prep_transpose<<<dim3(128), dim3(256), 0, stream>>>(Mn, MnT);
    fused_attn<<<dim3(1024), dim3(512), 0, stream>>>(x, Mn, MnT, recon, match);
}